// Round 2
// baseline (964.094 us; speedup 1.0000x reference)
//
#include <hip/hip_runtime.h>
#include <hip/hip_bf16.h>
#include <cstdint>
#include <cstddef>

#define N_NODES 50000
#define N_EDGES 1600000
#define HID 128
#define PCAT_N 384
#define EPSV 1e-12f

typedef __bf16 bf16_t;
typedef __bf16 bf16x8 __attribute__((ext_vector_type(8)));
typedef float f32x4 __attribute__((ext_vector_type(4)));

__device__ __forceinline__ float bf2f_lo(unsigned u) {
    return __builtin_bit_cast(float, u << 16);
}
__device__ __forceinline__ float bf2f_hi(unsigned u) {
    return __builtin_bit_cast(float, u & 0xFFFF0000u);
}
__device__ __forceinline__ unsigned short f2bf_rne(float x) {
    unsigned u = __builtin_bit_cast(unsigned, x);
    u += 0x7FFFu + ((u >> 16) & 1u);
    return (unsigned short)(u >> 16);
}
__device__ __forceinline__ float silu_f(float x) {
    return x / (1.0f + __expf(-x));
}

// ---------------------------------------------------------------------------
// Prep: build bf16 transposed weight blocks.
// wcatT[n][k], n in [0,384): n<128 -> W1a^T, n<256 -> W1b^T, else Wv^T.
// w2t[n][k] = W2[k][n].
// ---------------------------------------------------------------------------
__global__ void k_prepw(const float* __restrict__ W1, const float* __restrict__ W2,
                        const float* __restrict__ Wv, bf16_t* __restrict__ wcatT,
                        bf16_t* __restrict__ w2t) {
    int idx = blockIdx.x * blockDim.x + threadIdx.x;
    if (idx < 384 * 128) {
        int n = idx >> 7, k = idx & 127;
        float v;
        if (n < 128)      v = W1[k * 128 + n];
        else if (n < 256) v = W1[(128 + k) * 128 + (n - 128)];
        else              v = Wv[k * 128 + (n - 256)];
        wcatT[idx] = __builtin_bit_cast(bf16_t, f2bf_rne(v));
    } else if (idx < 384 * 128 + 128 * 128) {
        int j = idx - 384 * 128;
        int n = j >> 7, k = j & 127;
        w2t[j] = __builtin_bit_cast(bf16_t, f2bf_rne(W2[k * 128 + n]));
    }
}

// ---------------------------------------------------------------------------
// Node projection: pcat[i][0:384] = bf16( h[i] @ [W1a | W1b | Wv] )
// Tile: 64 rows x 384 cols per block, 4 waves each doing 64x96.
// ---------------------------------------------------------------------------
__global__ __launch_bounds__(256) void k_nodeproj(
    const float* __restrict__ h, const bf16_t* __restrict__ wcatT,
    bf16_t* __restrict__ pcat) {
    __shared__ bf16_t As[64 * 136];
    int t = threadIdx.x;
    int r0 = blockIdx.x * 64;
    // stage A (h rows, fp32 -> bf16)
    {
        int r = t >> 2, cbase = (t & 3) * 32;
        int gr = r0 + r;
        if (gr >= N_NODES) gr = 0;
        const float* src = h + (size_t)gr * 128 + cbase;
        bf16_t* dst = As + r * 136 + cbase;
#pragma unroll
        for (int i = 0; i < 4; ++i) {
            float4 v0 = *reinterpret_cast<const float4*>(src + i * 8);
            float4 v1 = *reinterpret_cast<const float4*>(src + i * 8 + 4);
            uint4 pk;
            pk.x = (unsigned)f2bf_rne(v0.x) | ((unsigned)f2bf_rne(v0.y) << 16);
            pk.y = (unsigned)f2bf_rne(v0.z) | ((unsigned)f2bf_rne(v0.w) << 16);
            pk.z = (unsigned)f2bf_rne(v1.x) | ((unsigned)f2bf_rne(v1.y) << 16);
            pk.w = (unsigned)f2bf_rne(v1.z) | ((unsigned)f2bf_rne(v1.w) << 16);
            *reinterpret_cast<uint4*>(dst + i * 8) = pk;
        }
    }
    __syncthreads();
    int lane = t & 63, w = t >> 6;
    f32x4 acc[4][6] = {};
#pragma unroll
    for (int kk = 0; kk < 4; ++kk) {
        bf16x8 af[4], bfr[6];
#pragma unroll
        for (int fm = 0; fm < 4; ++fm)
            af[fm] = *reinterpret_cast<const bf16x8*>(
                As + (fm * 16 + (lane & 15)) * 136 + kk * 32 + (lane >> 4) * 8);
#pragma unroll
        for (int fn = 0; fn < 6; ++fn) {
            int n = w * 96 + fn * 16 + (lane & 15);
            bfr[fn] = *reinterpret_cast<const bf16x8*>(
                wcatT + (size_t)n * 128 + kk * 32 + (lane >> 4) * 8);
        }
#pragma unroll
        for (int fm = 0; fm < 4; ++fm)
#pragma unroll
            for (int fn = 0; fn < 6; ++fn)
                acc[fm][fn] = __builtin_amdgcn_mfma_f32_16x16x32_bf16(
                    af[fm], bfr[fn], acc[fm][fn], 0, 0, 0);
    }
#pragma unroll
    for (int fm = 0; fm < 4; ++fm) {
#pragma unroll
        for (int j = 0; j < 4; ++j) {
            int row = r0 + fm * 16 + (lane >> 4) * 4 + j;
            if (row < N_NODES) {
#pragma unroll
                for (int fn = 0; fn < 6; ++fn) {
                    int col = w * 96 + fn * 16 + (lane & 15);
                    pcat[(size_t)row * PCAT_N + col] =
                        __builtin_bit_cast(bf16_t, f2bf_rne(acc[fm][fn][j]));
                }
            }
        }
    }
}

// ---------------------------------------------------------------------------
// CSR build
// ---------------------------------------------------------------------------
__global__ void k_hist(const int* __restrict__ eidx, int* __restrict__ hist) {
    int stride = gridDim.x * blockDim.x;
    for (int e = blockIdx.x * blockDim.x + threadIdx.x; e < N_EDGES; e += stride)
        atomicAdd(&hist[eidx[e]], 1);
}

__global__ __launch_bounds__(1024) void k_scan(const int* __restrict__ hist,
                                               int* __restrict__ row_start,
                                               int* __restrict__ cursor) {
    __shared__ int partial[1024];
    int t = threadIdx.x;
    const int C = (N_NODES + 1023) / 1024;  // 49
    int base = t * C;
    int sum = 0;
    for (int i = 0; i < C; ++i) {
        int j = base + i;
        if (j < N_NODES) sum += hist[j];
    }
    partial[t] = sum;
    __syncthreads();
    for (int off = 1; off < 1024; off <<= 1) {
        int v = (t >= off) ? partial[t - off] : 0;
        __syncthreads();
        partial[t] += v;
        __syncthreads();
    }
    int run = partial[t] - sum;  // exclusive prefix
    for (int i = 0; i < C; ++i) {
        int j = base + i;
        if (j < N_NODES) {
            row_start[j] = run;
            cursor[j] = run;
            run += hist[j];
        }
    }
    if (t == 1023) row_start[N_NODES] = partial[1023];
}

__global__ void k_scatter(const int* __restrict__ eidx, int* __restrict__ cursor,
                          int* __restrict__ edge_list) {
    int stride = gridDim.x * blockDim.x;
    for (int e = blockIdx.x * blockDim.x + threadIdx.x; e < N_EDGES; e += stride) {
        int d = eidx[e];
        int pos = atomicAdd(&cursor[d], 1);
        edge_list[pos] = e;
    }
}

// ---------------------------------------------------------------------------
// Fused edge kernel: assemble X1 = silu(Pa[dst]+Pb[src]+pos-term+b1) in LDS,
// layer2 via MFMA, layer3 dot + reduce -> scores.
// Block: 128 edges, 256 threads (4 waves: 2x2 over 128 edges x 128 cols).
// ---------------------------------------------------------------------------
__global__ __launch_bounds__(256) void k_edge(
    const bf16_t* __restrict__ pcat, const bf16_t* __restrict__ w2t,
    const int* __restrict__ eidx, const float* __restrict__ rel_pos,
    const float* __restrict__ dist, const float* __restrict__ W1,
    const float* __restrict__ b1, const float* __restrict__ b2,
    const float* __restrict__ W3, const float* __restrict__ b3,
    float* __restrict__ scores) {
    __shared__ bf16_t Ax[128 * 136];
    __shared__ bf16_t Wb[128 * 136];
    __shared__ int s_dst[128];
    __shared__ int s_src[128];
    __shared__ float4 s_rp[128];
    __shared__ float s_sc[128];

    int t = threadIdx.x;
    int e0 = blockIdx.x * 128;
    if (t < 128) {
        int e = e0 + t;
        s_dst[t] = eidx[e];
        s_src[t] = eidx[N_EDGES + e];
        s_rp[t] = make_float4(rel_pos[(size_t)e * 3], rel_pos[(size_t)e * 3 + 1],
                              rel_pos[(size_t)e * 3 + 2], dist[e]);
        s_sc[t] = b3[0];
    }
    // stage W2^T into LDS (padded stride 136)
    {
        int r = t >> 1, hh = (t & 1) * 64;
        const bf16_t* src = w2t + r * 128 + hh;
        bf16_t* dstp = Wb + r * 136 + hh;
#pragma unroll
        for (int i = 0; i < 8; ++i)
            *reinterpret_cast<uint4*>(dstp + i * 8) =
                *reinterpret_cast<const uint4*>(src + i * 8);
    }
    int lane = t & 63, w = t >> 6;
    int c0 = 2 * lane;
    // per-lane positional weights for its two columns (loaded once)
    float wA0 = W1[256 * 128 + c0], wA1 = W1[257 * 128 + c0];
    float wA2 = W1[258 * 128 + c0], wA3 = W1[259 * 128 + c0];
    float bA = b1[c0];
    float wB0 = W1[256 * 128 + c0 + 1], wB1 = W1[257 * 128 + c0 + 1];
    float wB2 = W1[258 * 128 + c0 + 1], wB3 = W1[259 * 128 + c0 + 1];
    float bB = b1[c0 + 1];
    __syncthreads();

    // phase 1: assembly. wave w handles edges [w*32, w*32+32)
#pragma unroll 4
    for (int i = 0; i < 32; ++i) {
        int e = w * 32 + i;
        int dn = s_dst[e], sn = s_src[e];
        float4 rp = s_rp[e];
        unsigned pa = *reinterpret_cast<const unsigned*>(pcat + (size_t)dn * PCAT_N + c0);
        unsigned pb = *reinterpret_cast<const unsigned*>(pcat + (size_t)sn * PCAT_N + 128 + c0);
        float x0 = bf2f_lo(pa) + bf2f_lo(pb) +
                   rp.x * wA0 + rp.y * wA1 + rp.z * wA2 + rp.w * wA3 + bA;
        float x1 = bf2f_hi(pa) + bf2f_hi(pb) +
                   rp.x * wB0 + rp.y * wB1 + rp.z * wB2 + rp.w * wB3 + bB;
        float y0 = silu_f(x0), y1 = silu_f(x1);
        unsigned pk = (unsigned)f2bf_rne(y0) | ((unsigned)f2bf_rne(y1) << 16);
        *reinterpret_cast<unsigned*>(Ax + e * 136 + c0) = pk;
    }
    __syncthreads();

    // phase 2: layer2 MFMA. wave (wm,wn) does 64x64 tile.
    int wm = w >> 1, wn = w & 1;
    f32x4 acc[4][4] = {};
#pragma unroll
    for (int kk = 0; kk < 4; ++kk) {
        bf16x8 af[4], bfr[4];
#pragma unroll
        for (int fm = 0; fm < 4; ++fm)
            af[fm] = *reinterpret_cast<const bf16x8*>(
                Ax + (wm * 64 + fm * 16 + (lane & 15)) * 136 + kk * 32 + (lane >> 4) * 8);
#pragma unroll
        for (int fn = 0; fn < 4; ++fn)
            bfr[fn] = *reinterpret_cast<const bf16x8*>(
                Wb + (wn * 64 + fn * 16 + (lane & 15)) * 136 + kk * 32 + (lane >> 4) * 8);
#pragma unroll
        for (int fm = 0; fm < 4; ++fm)
#pragma unroll
            for (int fn = 0; fn < 4; ++fn)
                acc[fm][fn] = __builtin_amdgcn_mfma_f32_16x16x32_bf16(
                    af[fm], bfr[fn], acc[fm][fn], 0, 0, 0);
    }

    // phase 3: layer3 (silu + dot with W3), reduce across 16 lanes, LDS-combine
    float w3v[4], b2v[4];
#pragma unroll
    for (int fn = 0; fn < 4; ++fn) {
        int n = wn * 64 + fn * 16 + (lane & 15);
        w3v[fn] = W3[n];
        b2v[fn] = b2[n];
    }
#pragma unroll
    for (int fm = 0; fm < 4; ++fm) {
        float pj[4] = {0.f, 0.f, 0.f, 0.f};
#pragma unroll
        for (int fn = 0; fn < 4; ++fn) {
#pragma unroll
            for (int j = 0; j < 4; ++j)
                pj[j] += silu_f(acc[fm][fn][j] + b2v[fn]) * w3v[fn];
        }
#pragma unroll
        for (int j = 0; j < 4; ++j) {
            float v = pj[j];
            v += __shfl_xor(v, 1);
            v += __shfl_xor(v, 2);
            v += __shfl_xor(v, 4);
            v += __shfl_xor(v, 8);
            if ((lane & 15) == 0)
                atomicAdd(&s_sc[wm * 64 + fm * 16 + (lane >> 4) * 4 + j], v);
        }
    }
    __syncthreads();
    if (t < 128) scores[e0 + t] = s_sc[t];
}

// ---------------------------------------------------------------------------
// Aggregation: one wave per node. Softmax over incoming edges + weighted
// accumulation of hv rows (pcat cols 256..383). out = h + sum.
// ---------------------------------------------------------------------------
__global__ __launch_bounds__(256) void k_agg(
    const float* __restrict__ h, const bf16_t* __restrict__ pcat,
    const float* __restrict__ scores, const int* __restrict__ row_start,
    const int* __restrict__ edge_list, const int* __restrict__ eidx,
    const float* __restrict__ nw, float* __restrict__ out) {
    __shared__ float s_coef[4][64];
    __shared__ int s_sv[4][64];
    int t = threadIdx.x, lane = t & 63, w = t >> 6;
    int node = blockIdx.x * 4 + w;
    if (node >= N_NODES) return;
    int s = row_start[node];
    int deg = row_start[node + 1] - s;
    float acc0 = 0.f, acc1 = 0.f;
    if (deg > 0) {
        float mx = -1e30f;
        for (int i = lane; i < deg; i += 64)
            mx = fmaxf(mx, scores[edge_list[s + i]]);
#pragma unroll
        for (int m = 32; m >= 1; m >>= 1) mx = fmaxf(mx, __shfl_xor(mx, m));
        float sm = 0.f;
        for (int i = lane; i < deg; i += 64)
            sm += __expf(scores[edge_list[s + i]] - mx);
#pragma unroll
        for (int m = 32; m >= 1; m >>= 1) sm += __shfl_xor(sm, m);
        float inv = 1.0f / (sm + EPSV);
        for (int base = 0; base < deg; base += 64) {
            int i = base + lane;
            if (i < deg) {
                int e = edge_list[s + i];
                int sv = eidx[N_EDGES + e];
                s_coef[w][lane] = __expf(scores[e] - mx) * inv * nw[sv];
                s_sv[w][lane] = sv;
            }
            asm volatile("s_waitcnt lgkmcnt(0)" ::: "memory");
            int m = deg - base;
            if (m > 64) m = 64;
#pragma unroll 4
            for (int j = 0; j < m; ++j) {
                float c = s_coef[w][j];
                int sv = s_sv[w][j];
                unsigned hv = *reinterpret_cast<const unsigned*>(
                    pcat + (size_t)sv * PCAT_N + 256 + 2 * lane);
                acc0 += c * bf2f_lo(hv);
                acc1 += c * bf2f_hi(hv);
            }
            asm volatile("s_waitcnt lgkmcnt(0)" ::: "memory");
        }
    }
    size_t o = (size_t)node * 128 + 2 * lane;
    float2 hv2 = *reinterpret_cast<const float2*>(h + o);
    float2 res;
    res.x = hv2.x + acc0;
    res.y = hv2.y + acc1;
    *reinterpret_cast<float2*>(out + o) = res;
}

// ---------------------------------------------------------------------------
extern "C" void kernel_launch(void* const* d_in, const int* in_sizes, int n_in,
                              void* d_out, int out_size, void* d_ws, size_t ws_size,
                              hipStream_t stream) {
    const float* h       = (const float*)d_in[0];
    const int*   eidx    = (const int*)d_in[1];
    const float* rel_pos = (const float*)d_in[2];
    const float* dist    = (const float*)d_in[3];
    const float* nw      = (const float*)d_in[4];
    const float* W1      = (const float*)d_in[5];
    const float* b1      = (const float*)d_in[6];
    const float* W2      = (const float*)d_in[7];
    const float* b2      = (const float*)d_in[8];
    const float* W3      = (const float*)d_in[9];
    const float* b3      = (const float*)d_in[10];
    const float* Wv      = (const float*)d_in[11];
    float* out = (float*)d_out;

    char* p = (char*)d_ws;
    auto carve = [&](size_t bytes) {
        char* r = p;
        p += (bytes + 255) & ~(size_t)255;
        return r;
    };
    bf16_t* pcat    = (bf16_t*)carve((size_t)N_NODES * PCAT_N * 2);
    bf16_t* wcatT   = (bf16_t*)carve(384 * 128 * 2);
    bf16_t* w2t     = (bf16_t*)carve(128 * 128 * 2);
    float* scores   = (float*)carve((size_t)N_EDGES * 4);
    int* hist       = (int*)carve((size_t)N_NODES * 4);
    int* row_start  = (int*)carve((size_t)(N_NODES + 1) * 4);
    int* cursor     = (int*)carve((size_t)N_NODES * 4);
    int* edge_list  = (int*)carve((size_t)N_EDGES * 4);

    hipMemsetAsync(hist, 0, (size_t)N_NODES * 4, stream);
    k_prepw<<<256, 256, 0, stream>>>(W1, W2, Wv, wcatT, w2t);
    k_nodeproj<<<(N_NODES + 63) / 64, 256, 0, stream>>>(h, wcatT, pcat);
    k_hist<<<2048, 256, 0, stream>>>(eidx, hist);
    k_scan<<<1, 1024, 0, stream>>>(hist, row_start, cursor);
    k_scatter<<<2048, 256, 0, stream>>>(eidx, cursor, edge_list);
    k_edge<<<N_EDGES / 128, 256, 0, stream>>>(pcat, w2t, eidx, rel_pos, dist,
                                              W1, b1, b2, W3, b3, scores);
    k_agg<<<(N_NODES + 3) / 4, 256, 0, stream>>>(h, pcat, scores, row_start,
                                                 edge_list, eidx, nw, out);
}

// Round 3
// 656.445 us; speedup vs baseline: 1.4687x; 1.4687x over previous
//
#include <hip/hip_runtime.h>
#include <hip/hip_bf16.h>
#include <cstdint>
#include <cstddef>

#define N_NODES 50000
#define N_EDGES 1600000
#define HID 128
#define PCAT_N 384
#define EPSV 1e-12f

typedef __bf16 bf16_t;
typedef __bf16 bf16x8 __attribute__((ext_vector_type(8)));
typedef float f32x4 __attribute__((ext_vector_type(4)));

__device__ __forceinline__ float bf2f_lo(unsigned u) {
    return __builtin_bit_cast(float, u << 16);
}
__device__ __forceinline__ float bf2f_hi(unsigned u) {
    return __builtin_bit_cast(float, u & 0xFFFF0000u);
}
__device__ __forceinline__ unsigned short f2bf_rne(float x) {
    unsigned u = __builtin_bit_cast(unsigned, x);
    u += 0x7FFFu + ((u >> 16) & 1u);
    return (unsigned short)(u >> 16);
}
// silu via fast rcp (v_rcp_f32, ~1ulp) instead of IEEE division (~10 VALU ops)
__device__ __forceinline__ float silu_f(float x) {
    return x * __builtin_amdgcn_rcpf(1.0f + __expf(-x));
}

// ---------------------------------------------------------------------------
// Prep: build bf16 transposed weight blocks.
// wcatT[n][k], n in [0,384): n<128 -> W1a^T, n<256 -> W1b^T, else Wv^T.
// w2t[n][k] = W2[k][n].
// ---------------------------------------------------------------------------
__global__ void k_prepw(const float* __restrict__ W1, const float* __restrict__ W2,
                        const float* __restrict__ Wv, bf16_t* __restrict__ wcatT,
                        bf16_t* __restrict__ w2t) {
    int idx = blockIdx.x * blockDim.x + threadIdx.x;
    if (idx < 384 * 128) {
        int n = idx >> 7, k = idx & 127;
        float v;
        if (n < 128)      v = W1[k * 128 + n];
        else if (n < 256) v = W1[(128 + k) * 128 + (n - 128)];
        else              v = Wv[k * 128 + (n - 256)];
        wcatT[idx] = __builtin_bit_cast(bf16_t, f2bf_rne(v));
    } else if (idx < 384 * 128 + 128 * 128) {
        int j = idx - 384 * 128;
        int n = j >> 7, k = j & 127;
        w2t[j] = __builtin_bit_cast(bf16_t, f2bf_rne(W2[k * 128 + n]));
    }
}

// ---------------------------------------------------------------------------
// Node projection: pcat[i][0:384] = bf16( h[i] @ [W1a | W1b | Wv] ),
// with value cols (>=256) pre-scaled by node_weight[i].
// ---------------------------------------------------------------------------
__global__ __launch_bounds__(256) void k_nodeproj(
    const float* __restrict__ h, const bf16_t* __restrict__ wcatT,
    const float* __restrict__ nw, bf16_t* __restrict__ pcat) {
    __shared__ bf16_t As[64 * 136];
    int t = threadIdx.x;
    int r0 = blockIdx.x * 64;
    {
        int r = t >> 2, cbase = (t & 3) * 32;
        int gr = r0 + r;
        if (gr >= N_NODES) gr = 0;
        const float* src = h + (size_t)gr * 128 + cbase;
        bf16_t* dst = As + r * 136 + cbase;
#pragma unroll
        for (int i = 0; i < 4; ++i) {
            float4 v0 = *reinterpret_cast<const float4*>(src + i * 8);
            float4 v1 = *reinterpret_cast<const float4*>(src + i * 8 + 4);
            uint4 pk;
            pk.x = (unsigned)f2bf_rne(v0.x) | ((unsigned)f2bf_rne(v0.y) << 16);
            pk.y = (unsigned)f2bf_rne(v0.z) | ((unsigned)f2bf_rne(v0.w) << 16);
            pk.z = (unsigned)f2bf_rne(v1.x) | ((unsigned)f2bf_rne(v1.y) << 16);
            pk.w = (unsigned)f2bf_rne(v1.z) | ((unsigned)f2bf_rne(v1.w) << 16);
            *reinterpret_cast<uint4*>(dst + i * 8) = pk;
        }
    }
    __syncthreads();
    int lane = t & 63, w = t >> 6;
    f32x4 acc[4][6] = {};
#pragma unroll
    for (int kk = 0; kk < 4; ++kk) {
        bf16x8 af[4], bfr[6];
#pragma unroll
        for (int fm = 0; fm < 4; ++fm)
            af[fm] = *reinterpret_cast<const bf16x8*>(
                As + (fm * 16 + (lane & 15)) * 136 + kk * 32 + (lane >> 4) * 8);
#pragma unroll
        for (int fn = 0; fn < 6; ++fn) {
            int n = w * 96 + fn * 16 + (lane & 15);
            bfr[fn] = *reinterpret_cast<const bf16x8*>(
                wcatT + (size_t)n * 128 + kk * 32 + (lane >> 4) * 8);
        }
#pragma unroll
        for (int fm = 0; fm < 4; ++fm)
#pragma unroll
            for (int fn = 0; fn < 6; ++fn)
                acc[fm][fn] = __builtin_amdgcn_mfma_f32_16x16x32_bf16(
                    af[fm], bfr[fn], acc[fm][fn], 0, 0, 0);
    }
#pragma unroll
    for (int fm = 0; fm < 4; ++fm) {
#pragma unroll
        for (int j = 0; j < 4; ++j) {
            int row = r0 + fm * 16 + (lane >> 4) * 4 + j;
            if (row < N_NODES) {
                float nwv = (w >= 2) ? nw[row] : 1.0f;
#pragma unroll
                for (int fn = 0; fn < 6; ++fn) {
                    int colbase = w * 96 + fn * 16;
                    float v = acc[fm][fn][j];
                    if (colbase >= 256) v *= nwv;
                    pcat[(size_t)row * PCAT_N + colbase + (lane & 15)] =
                        __builtin_bit_cast(bf16_t, f2bf_rne(v));
                }
            }
        }
    }
}

// ---------------------------------------------------------------------------
// CSR row pointers
// ---------------------------------------------------------------------------
__global__ void k_hist(const int* __restrict__ eidx, int* __restrict__ hist) {
    int stride = gridDim.x * blockDim.x;
    for (int e = blockIdx.x * blockDim.x + threadIdx.x; e < N_EDGES; e += stride)
        atomicAdd(&hist[eidx[e]], 1);
}

__global__ __launch_bounds__(1024) void k_scan(const int* __restrict__ hist,
                                               int* __restrict__ row_start,
                                               int* __restrict__ cursor) {
    __shared__ int partial[1024];
    int t = threadIdx.x;
    const int C = (N_NODES + 1023) / 1024;  // 49
    int base = t * C;
    int sum = 0;
    for (int i = 0; i < C; ++i) {
        int j = base + i;
        if (j < N_NODES) sum += hist[j];
    }
    partial[t] = sum;
    __syncthreads();
    for (int off = 1; off < 1024; off <<= 1) {
        int v = (t >= off) ? partial[t - off] : 0;
        __syncthreads();
        partial[t] += v;
        __syncthreads();
    }
    int run = partial[t] - sum;  // exclusive prefix
    for (int i = 0; i < C; ++i) {
        int j = base + i;
        if (j < N_NODES) {
            row_start[j] = run;
            cursor[j] = run;
            run += hist[j];
        }
    }
    if (t == 1023) row_start[N_NODES] = partial[1023];
}

// ---------------------------------------------------------------------------
// Fused edge kernel: assemble X1 = silu(Pa[dst]+Pb[src]+pos-term+b1) in LDS,
// layer2 MFMA (W2 frags straight from L1/L2-resident global), layer3 dot ->
// score, then scatter (score, src) into CSR slot via cursor atomic.
// Block: 128 edges, 256 threads (4 waves: 2x2 over 128 edges x 128 cols).
// ---------------------------------------------------------------------------
__global__ __launch_bounds__(256, 3) void k_edge(
    const bf16_t* __restrict__ pcat, const bf16_t* __restrict__ w2t,
    const int* __restrict__ eidx, const float* __restrict__ rel_pos,
    const float* __restrict__ dist, const float* __restrict__ W1,
    const float* __restrict__ b1, const float* __restrict__ b2,
    const float* __restrict__ W3, const float* __restrict__ b3,
    int* __restrict__ cursor, float* __restrict__ scores_csr,
    int* __restrict__ src_csr) {
    __shared__ bf16_t Ax[128 * 136];
    __shared__ int s_dst[128];
    __shared__ int s_src[128];
    __shared__ float4 s_rp[128];
    __shared__ float s_sc[128];

    int t = threadIdx.x;
    int e0 = blockIdx.x * 128;
    if (t < 128) {
        int e = e0 + t;
        s_dst[t] = eidx[e];
        s_src[t] = eidx[N_EDGES + e];
        s_rp[t] = make_float4(rel_pos[(size_t)e * 3], rel_pos[(size_t)e * 3 + 1],
                              rel_pos[(size_t)e * 3 + 2], dist[e]);
        s_sc[t] = b3[0];
    }
    int lane = t & 63, w = t >> 6;
    int c0 = 2 * lane;
    float wA0 = W1[256 * 128 + c0], wA1 = W1[257 * 128 + c0];
    float wA2 = W1[258 * 128 + c0], wA3 = W1[259 * 128 + c0];
    float bA = b1[c0];
    float wB0 = W1[256 * 128 + c0 + 1], wB1 = W1[257 * 128 + c0 + 1];
    float wB2 = W1[258 * 128 + c0 + 1], wB3 = W1[259 * 128 + c0 + 1];
    float bB = b1[c0 + 1];
    __syncthreads();

    // phase 1: assembly. wave w handles edges [w*32, w*32+32)
#pragma unroll 4
    for (int i = 0; i < 32; ++i) {
        int e = w * 32 + i;
        int dn = s_dst[e], sn = s_src[e];
        float4 rp = s_rp[e];
        unsigned pa = *reinterpret_cast<const unsigned*>(pcat + (size_t)dn * PCAT_N + c0);
        unsigned pb = *reinterpret_cast<const unsigned*>(pcat + (size_t)sn * PCAT_N + 128 + c0);
        float x0 = bf2f_lo(pa) + bf2f_lo(pb) +
                   rp.x * wA0 + rp.y * wA1 + rp.z * wA2 + rp.w * wA3 + bA;
        float x1 = bf2f_hi(pa) + bf2f_hi(pb) +
                   rp.x * wB0 + rp.y * wB1 + rp.z * wB2 + rp.w * wB3 + bB;
        float y0 = silu_f(x0), y1 = silu_f(x1);
        unsigned pk = (unsigned)f2bf_rne(y0) | ((unsigned)f2bf_rne(y1) << 16);
        *reinterpret_cast<unsigned*>(Ax + e * 136 + c0) = pk;
    }
    __syncthreads();

    // phase 2: layer2 MFMA. wave (wm,wn) does 64x64 tile. B frags from global.
    int wm = w >> 1, wn = w & 1;
    f32x4 acc[4][4] = {};
#pragma unroll
    for (int kk = 0; kk < 4; ++kk) {
        bf16x8 af[4], bfr[4];
#pragma unroll
        for (int fn = 0; fn < 4; ++fn) {
            int n = wn * 64 + fn * 16 + (lane & 15);
            bfr[fn] = *reinterpret_cast<const bf16x8*>(
                w2t + (size_t)n * 128 + kk * 32 + (lane >> 4) * 8);
        }
#pragma unroll
        for (int fm = 0; fm < 4; ++fm)
            af[fm] = *reinterpret_cast<const bf16x8*>(
                Ax + (wm * 64 + fm * 16 + (lane & 15)) * 136 + kk * 32 + (lane >> 4) * 8);
#pragma unroll
        for (int fm = 0; fm < 4; ++fm)
#pragma unroll
            for (int fn = 0; fn < 4; ++fn)
                acc[fm][fn] = __builtin_amdgcn_mfma_f32_16x16x32_bf16(
                    af[fm], bfr[fn], acc[fm][fn], 0, 0, 0);
    }

    // phase 3: layer3 (silu + dot with W3), 16-lane reduce, LDS-combine
    float w3v[4], b2v[4];
#pragma unroll
    for (int fn = 0; fn < 4; ++fn) {
        int n = wn * 64 + fn * 16 + (lane & 15);
        w3v[fn] = W3[n];
        b2v[fn] = b2[n];
    }
#pragma unroll
    for (int fm = 0; fm < 4; ++fm) {
        float pj[4] = {0.f, 0.f, 0.f, 0.f};
#pragma unroll
        for (int fn = 0; fn < 4; ++fn) {
#pragma unroll
            for (int j = 0; j < 4; ++j)
                pj[j] += silu_f(acc[fm][fn][j] + b2v[fn]) * w3v[fn];
        }
#pragma unroll
        for (int j = 0; j < 4; ++j) {
            float v = pj[j];
            v += __shfl_xor(v, 1);
            v += __shfl_xor(v, 2);
            v += __shfl_xor(v, 4);
            v += __shfl_xor(v, 8);
            if ((lane & 15) == 0)
                atomicAdd(&s_sc[wm * 64 + fm * 16 + (lane >> 4) * 4 + j], v);
        }
    }
    __syncthreads();
    // scatter (score, src) into this dst's CSR segment
    if (t < 128) {
        int pos = atomicAdd(&cursor[s_dst[t]], 1);
        scores_csr[pos] = s_sc[t];
        src_csr[pos] = s_src[t];
    }
}

// ---------------------------------------------------------------------------
// Aggregation: one wave per node. Coalesced CSR reads; hv rows already
// nw-scaled. out = h + sum(alpha * hv[src]).
// ---------------------------------------------------------------------------
__global__ __launch_bounds__(256) void k_agg(
    const float* __restrict__ h, const bf16_t* __restrict__ pcat,
    const float* __restrict__ scores_csr, const int* __restrict__ src_csr,
    const int* __restrict__ row_start, float* __restrict__ out) {
    __shared__ float s_coef[4][64];
    __shared__ int s_sv[4][64];
    int t = threadIdx.x, lane = t & 63, w = t >> 6;
    int node = blockIdx.x * 4 + w;
    if (node >= N_NODES) return;
    int s = row_start[node];
    int deg = row_start[node + 1] - s;
    float acc0 = 0.f, acc1 = 0.f;
    if (deg > 0) {
        float mx = -1e30f;
        for (int i = lane; i < deg; i += 64)
            mx = fmaxf(mx, scores_csr[s + i]);
#pragma unroll
        for (int m = 32; m >= 1; m >>= 1) mx = fmaxf(mx, __shfl_xor(mx, m));
        float sm = 0.f;
        for (int i = lane; i < deg; i += 64)
            sm += __expf(scores_csr[s + i] - mx);
#pragma unroll
        for (int m = 32; m >= 1; m >>= 1) sm += __shfl_xor(sm, m);
        float inv = 1.0f / (sm + EPSV);
        for (int base = 0; base < deg; base += 64) {
            int i = base + lane;
            if (i < deg) {
                s_coef[w][lane] = __expf(scores_csr[s + i] - mx) * inv;
                s_sv[w][lane] = src_csr[s + i];
            }
            asm volatile("s_waitcnt lgkmcnt(0)" ::: "memory");
            int m = deg - base;
            if (m > 64) m = 64;
#pragma unroll 4
            for (int j = 0; j < m; ++j) {
                float c = s_coef[w][j];
                int sv = s_sv[w][j];
                unsigned hv = *reinterpret_cast<const unsigned*>(
                    pcat + (size_t)sv * PCAT_N + 256 + 2 * lane);
                acc0 += c * bf2f_lo(hv);
                acc1 += c * bf2f_hi(hv);
            }
            asm volatile("s_waitcnt lgkmcnt(0)" ::: "memory");
        }
    }
    size_t o = (size_t)node * 128 + 2 * lane;
    float2 hv2 = *reinterpret_cast<const float2*>(h + o);
    float2 res;
    res.x = hv2.x + acc0;
    res.y = hv2.y + acc1;
    *reinterpret_cast<float2*>(out + o) = res;
}

// ---------------------------------------------------------------------------
extern "C" void kernel_launch(void* const* d_in, const int* in_sizes, int n_in,
                              void* d_out, int out_size, void* d_ws, size_t ws_size,
                              hipStream_t stream) {
    const float* h       = (const float*)d_in[0];
    const int*   eidx    = (const int*)d_in[1];
    const float* rel_pos = (const float*)d_in[2];
    const float* dist    = (const float*)d_in[3];
    const float* nw      = (const float*)d_in[4];
    const float* W1      = (const float*)d_in[5];
    const float* b1      = (const float*)d_in[6];
    const float* W2      = (const float*)d_in[7];
    const float* b2      = (const float*)d_in[8];
    const float* W3      = (const float*)d_in[9];
    const float* b3      = (const float*)d_in[10];
    const float* Wv      = (const float*)d_in[11];
    float* out = (float*)d_out;

    char* p = (char*)d_ws;
    auto carve = [&](size_t bytes) {
        char* r = p;
        p += (bytes + 255) & ~(size_t)255;
        return r;
    };
    bf16_t* pcat      = (bf16_t*)carve((size_t)N_NODES * PCAT_N * 2);
    bf16_t* wcatT     = (bf16_t*)carve(384 * 128 * 2);
    bf16_t* w2t       = (bf16_t*)carve(128 * 128 * 2);
    float* scores_csr = (float*)carve((size_t)N_EDGES * 4);
    int* src_csr      = (int*)carve((size_t)N_EDGES * 4);
    int* hist         = (int*)carve((size_t)N_NODES * 4);
    int* row_start    = (int*)carve((size_t)(N_NODES + 1) * 4);
    int* cursor       = (int*)carve((size_t)N_NODES * 4);

    hipMemsetAsync(hist, 0, (size_t)N_NODES * 4, stream);
    k_prepw<<<256, 256, 0, stream>>>(W1, W2, Wv, wcatT, w2t);
    k_nodeproj<<<(N_NODES + 63) / 64, 256, 0, stream>>>(h, wcatT, nw, pcat);
    k_hist<<<2048, 256, 0, stream>>>(eidx, hist);
    k_scan<<<1, 1024, 0, stream>>>(hist, row_start, cursor);
    k_edge<<<N_EDGES / 128, 256, 0, stream>>>(pcat, w2t, eidx, rel_pos, dist,
                                              W1, b1, b2, W3, b3,
                                              cursor, scores_csr, src_csr);
    k_agg<<<(N_NODES + 3) / 4, 256, 0, stream>>>(h, pcat, scores_csr, src_csr,
                                                 row_start, out);
}